// Round 1
// baseline (5454.082 us; speedup 1.0000x reference)
//
#include <hip/hip_runtime.h>
#include <hip/hip_bf16.h>

#define SEQ_   128
#define NCLS_  50257
#define EMB_   1024
#define HID_   1024
#define BATCH_ 1024
#define G4_    4096

typedef __attribute__((ext_vector_type(8))) short short8;
typedef __attribute__((ext_vector_type(4))) float f32x4;

__device__ __forceinline__ void async_copy16(void* lds, const void* g) {
  __builtin_amdgcn_global_load_lds(
      (const __attribute__((address_space(1))) void*)g,
      (__attribute__((address_space(3))) void*)lds, 16, 0, 0);
}

// D = A(16x32) * B(32x16) + D, bf16 inputs, fp32 acc. Inline asm avoids the
// builtin short8/__bf16 signature ambiguity across ROCm versions.
__device__ __forceinline__ void mfma_acc(f32x4& c, const short8& a, const short8& b) {
  asm("v_mfma_f32_16x16x32_bf16 %0, %1, %2, %0" : "+v"(c) : "v"(a), "v"(b));
}

__device__ __forceinline__ float sigmoidf_(float x) {
  return 1.f / (1.f + __expf(-x));
}
__device__ __forceinline__ float tanhf_(float x) {
  x = fminf(12.f, fmaxf(-12.f, x));
  float e = __expf(2.f * x);
  return (e - 1.f) / (e + 1.f);
}

// ---------------------------------------------------------------------------
// C[M,N] = A[M,K](bf16,row-major) x Bt[N,K](bf16,row-major = B^T), fp32 acc.
// EPI 0: outB[row*os+col] = bf16(acc + bias0[col] + bias1[col])   (E_proj)
// EPI 1: outF[row*os+col] = acc + Eps[X[row,t]][col]              (gates)
// EPI 2: outF[row*os+col] = acc + bias0[col]  (col<Nreal guard)   (logits)
// BM=BN=128, BK=32, 4 waves (2x2), 64x64 per wave, mfma 16x16x32.
// ---------------------------------------------------------------------------
template <int EPI>
__global__ __launch_bounds__(256) void gemm_bt(
    const __hip_bfloat16* __restrict__ A, const __hip_bfloat16* __restrict__ Bt,
    float* __restrict__ outF, __hip_bfloat16* __restrict__ outB,
    int Mreal, int Nreal, int K, long ostride,
    const float* __restrict__ bias0, const float* __restrict__ bias1,
    const __hip_bfloat16* __restrict__ Eps, const int* __restrict__ X, int t) {
  __shared__ __align__(16) __hip_bfloat16 lA[128 * 32];
  __shared__ __align__(16) __hip_bfloat16 lB[128 * 32];

  const int tid = threadIdx.x;
  const int lane = tid & 63;
  const int w = tid >> 6;       // wave 0..3
  const int wm = w >> 1;        // 2x2 wave grid
  const int wn = w & 1;
  const int m0 = blockIdx.y * 128;
  const int n0 = blockIdx.x * 128;

  f32x4 acc[4][4];
#pragma unroll
  for (int i = 0; i < 4; ++i)
#pragma unroll
    for (int j = 0; j < 4; ++j) acc[i][j] = (f32x4)(0.0f);

  for (int k0 = 0; k0 < K; k0 += 32) {
    // ---- stage A,B tiles ([128][32] bf16, row-major, 64B/row) via async DMA
#pragma unroll
    for (int i = 0; i < 2; ++i) {
      const int chunk = w * 128 + i * 64 + lane;  // 16B chunk index
      const int row = chunk >> 2;
      const int kb = (chunk & 3) * 16;  // byte offset within row
      long ar = m0 + row; if (ar >= Mreal) ar = Mreal - 1;
      async_copy16((char*)lA + w * 2048 + i * 1024,
                   (const char*)A + (ar * (long)K + k0) * 2 + kb);
      long br = n0 + row; if (br >= Nreal) br = Nreal - 1;
      async_copy16((char*)lB + w * 2048 + i * 1024,
                   (const char*)Bt + (br * (long)K + k0) * 2 + kb);
    }
    __syncthreads();  // drains vmcnt before barrier

    // ---- fragments + MFMA
    const int kk = (lane >> 4) * 8;   // k element offset
    const int fr = lane & 15;         // row (A) / col (B) within fragment
    short8 aF[4], bF[4];
#pragma unroll
    for (int f = 0; f < 4; ++f) {
      aF[f] = *(const short8*)((const char*)lA + ((wm * 64 + f * 16 + fr) * 32 + kk) * 2);
      bF[f] = *(const short8*)((const char*)lB + ((wn * 64 + f * 16 + fr) * 32 + kk) * 2);
    }
#pragma unroll
    for (int fm = 0; fm < 4; ++fm)
#pragma unroll
      for (int fn = 0; fn < 4; ++fn) mfma_acc(acc[fm][fn], aF[fm], bF[fn]);
    __syncthreads();  // LDS reuse next iteration
  }

  // ---- epilogue. C/D layout: col = lane&15, row = (lane>>4)*4 + reg
  const int cn = lane & 15;
  const int rb = (lane >> 4) * 4;

  if (EPI == 1) {
#pragma unroll
    for (int fm = 0; fm < 4; ++fm) {
#pragma unroll
      for (int r = 0; r < 4; ++r) {
        const int row = m0 + wm * 64 + fm * 16 + rb + r;
        const int tok = X[row * SEQ_ + t];
        const __hip_bfloat16* erow = Eps + (long)tok * G4_;
#pragma unroll
        for (int fn = 0; fn < 4; ++fn) {
          const int col = n0 + wn * 64 + fn * 16 + cn;
          outF[(long)row * ostride + col] = acc[fm][fn][r] + __bfloat162float(erow[col]);
        }
      }
    }
  } else {
#pragma unroll
    for (int fn = 0; fn < 4; ++fn) {
      const int col = n0 + wn * 64 + fn * 16 + cn;
      float badd = 0.f;
      if (EPI == 0) badd = bias0[col] + bias1[col];
      else if (col < Nreal) badd = bias0[col];
#pragma unroll
      for (int fm = 0; fm < 4; ++fm) {
#pragma unroll
        for (int r = 0; r < 4; ++r) {
          const int row = m0 + wm * 64 + fm * 16 + rb + r;
          const float v = acc[fm][fn][r] + badd;
          if (EPI == 0) {
            if (row < Mreal) outB[(long)row * ostride + col] = __float2bfloat16(v);
          } else {
            if (col < Nreal) outF[(long)row * ostride + col] = v;
          }
        }
      }
    }
  }
}

// fp32 -> bf16 flat convert (float4 vectorized)
__global__ __launch_bounds__(256) void conv_bf16_k(const float* __restrict__ in,
                                                   __hip_bfloat16* __restrict__ out, int n4) {
  const int i = blockIdx.x * 256 + threadIdx.x;
  if (i >= n4) return;
  const float4 v = ((const float4*)in)[i];
  const int o = i * 4;
  out[o + 0] = __float2bfloat16(v.x);
  out[o + 1] = __float2bfloat16(v.y);
  out[o + 2] = __float2bfloat16(v.z);
  out[o + 3] = __float2bfloat16(v.w);
}

// in[R][C] fp32 -> out[C][R] bf16, 32x32 LDS-tiled
__global__ __launch_bounds__(256) void transpose_conv(const float* __restrict__ in,
                                                      __hip_bfloat16* __restrict__ out,
                                                      int R, int C) {
  __shared__ float tile[32][33];
  const int c0 = blockIdx.x * 32, r0 = blockIdx.y * 32;
  const int tx = threadIdx.x, ty = threadIdx.y;  // 32x8
#pragma unroll
  for (int i = 0; i < 4; ++i) {
    const int r = r0 + ty + i * 8, cc = c0 + tx;
    tile[ty + i * 8][tx] = (r < R && cc < C) ? in[(size_t)r * C + cc] : 0.f;
  }
  __syncthreads();
#pragma unroll
  for (int i = 0; i < 4; ++i) {
    const int ro = c0 + ty + i * 8, co = r0 + tx;
    if (ro < C && co < R) out[(size_t)ro * R + co] = __float2bfloat16(tile[tx][ty + i * 8]);
  }
}

// elementwise LSTM cell: gates[B,4H] (i,f,g,o blocks) -> c, h(bf16)
__global__ __launch_bounds__(256) void lstm_cell(const float* __restrict__ gates,
                                                 float* __restrict__ c,
                                                 __hip_bfloat16* __restrict__ hb) {
  const int idx = blockIdx.x * 256 + threadIdx.x;  // 0 .. B*H-1
  const int b = idx >> 10, h = idx & 1023;
  const float* g = gates + (long)b * G4_;
  const float iv = sigmoidf_(g[h]);
  const float fv = sigmoidf_(g[h + HID_]);
  const float gv = tanhf_(g[h + 2 * HID_]);
  const float ov = sigmoidf_(g[h + 3 * HID_]);
  const float cv = fv * c[idx] + iv * gv;
  c[idx] = cv;
  hb[idx] = __float2bfloat16(ov * tanhf_(cv));
}

extern "C" void kernel_launch(void* const* d_in, const int* in_sizes, int n_in,
                              void* d_out, int out_size, void* d_ws, size_t ws_size,
                              hipStream_t stream) {
  const int* X = (const int*)d_in[0];        // [1024,128]
  const float* C = (const float*)d_in[1];    // [50257,1024]
  const float* Wx = (const float*)d_in[2];   // [1024,4096]
  const float* bx = (const float*)d_in[3];   // [4096]
  const float* Wh = (const float*)d_in[4];   // [1024,4096]
  const float* bh = (const float*)d_in[5];   // [4096]
  const float* Wo = (const float*)d_in[6];   // [1024,50257]
  const float* bo = (const float*)d_in[7];   // [50257]
  float* out = (float*)d_out;                // [1024,50257]

  // ---- workspace carve (Cb region reused later for W_out^T)
  char* p = (char*)d_ws;
  const size_t szCb  = (size_t)NCLS_ * EMB_ * 2;   // 102.9 MB (shared: Cb / Wot)
  const size_t szWxt = (size_t)G4_ * EMB_ * 2;     // 8.4 MB
  const size_t szWht = (size_t)G4_ * HID_ * 2;     // 8.4 MB
  const size_t szEps = (size_t)NCLS_ * G4_ * 2;    // 411.7 MB
  const size_t szGat = (size_t)BATCH_ * G4_ * 4;   // 16.8 MB
  const size_t szC   = (size_t)BATCH_ * HID_ * 4;  // 4.2 MB
  const size_t szHb  = (size_t)BATCH_ * HID_ * 2;  // 2.1 MB
  if (ws_size < szCb + szWxt + szWht + szEps + szGat + szC + szHb) return;

  __hip_bfloat16* Cb  = (__hip_bfloat16*)p; p += szCb;
  __hip_bfloat16* Wxt = (__hip_bfloat16*)p; p += szWxt;
  __hip_bfloat16* Wht = (__hip_bfloat16*)p; p += szWht;
  __hip_bfloat16* Eps = (__hip_bfloat16*)p; p += szEps;
  float* gates        = (float*)p;          p += szGat;
  float* cbuf         = (float*)p;          p += szC;
  __hip_bfloat16* hb  = (__hip_bfloat16*)p; p += szHb;

  // 1. convert C -> bf16
  {
    const int n4 = NCLS_ * EMB_ / 4;
    conv_bf16_k<<<(n4 + 255) / 256, 256, 0, stream>>>(C, Cb, n4);
  }
  // 2. transpose+convert Wx, Wh -> [4H, K] bf16
  transpose_conv<<<dim3(G4_ / 32, EMB_ / 32), dim3(32, 8), 0, stream>>>(Wx, Wxt, EMB_, G4_);
  transpose_conv<<<dim3(G4_ / 32, HID_ / 32), dim3(32, 8), 0, stream>>>(Wh, Wht, HID_, G4_);

  // 3. E_proj[V,4H] = C @ Wx + bx + bh  (bf16 out)
  gemm_bt<0><<<dim3(G4_ / 128, (NCLS_ + 127) / 128), 256, 0, stream>>>(
      Cb, Wxt, nullptr, Eps, NCLS_, G4_, EMB_, G4_, bx, bh, nullptr, nullptr, 0);

  // 4. zero state
  hipMemsetAsync(cbuf, 0, szC, stream);
  hipMemsetAsync(hb, 0, szHb, stream);

  // 5. 128 sequential LSTM steps
  for (int t = 0; t < SEQ_; ++t) {
    gemm_bt<1><<<dim3(G4_ / 128, BATCH_ / 128), 256, 0, stream>>>(
        hb, Wht, gates, nullptr, BATCH_, G4_, HID_, G4_, nullptr, nullptr, Eps, X, t);
    lstm_cell<<<(BATCH_ * HID_) / 256, 256, 0, stream>>>(gates, cbuf, hb);
  }

  // 6. W_out^T into the Cb region (Cb dead after step 3's GEMM)
  __hip_bfloat16* Wot = Cb;
  transpose_conv<<<dim3((NCLS_ + 31) / 32, HID_ / 32), dim3(32, 8), 0, stream>>>(
      Wo, Wot, HID_, NCLS_);

  // 7. logits = h @ W_out + b_out  (fp32, full coverage of d_out)
  gemm_bt<2><<<dim3((NCLS_ + 127) / 128, BATCH_ / 128), 256, 0, stream>>>(
      hb, Wot, out, nullptr, BATCH_, NCLS_, HID_, NCLS_, bo, nullptr, nullptr, nullptr, 0);
}